// Round 14
// baseline (403.823 us; speedup 1.0000x reference)
//
#include <hip/hip_runtime.h>
#include <hip/hip_bf16.h>
#include <stdint.h>
#include <type_traits>

// B=16384, IN=1024, H=1024, K = IN+H = 2048
// Gate order: 0=i, 1=f, 2=o, 3=u
// ws: A_bf16 [16384][2048] @ 0 (64 MiB); B_bf16 [4][1024][2048] (j-major = W^T) @ 64 MiB

typedef short bf16x8 __attribute__((ext_vector_type(8)));
typedef unsigned short u16x8 __attribute__((ext_vector_type(8)));
typedef float f32x16 __attribute__((ext_vector_type(16)));

__device__ __forceinline__ unsigned short f2bf(float f) {
    union { float f; uint32_t u; } v; v.f = f;
    uint32_t r = v.u + 0x7FFFu + ((v.u >> 16) & 1u);   // RNE
    return (unsigned short)(r >> 16);
}

__device__ __forceinline__ float fsig(float x) { return 1.0f / (1.0f + __expf(-x)); }
__device__ __forceinline__ float ftanh(float x) { return 2.0f * fsig(2.0f * x) - 1.0f; }

// ---------------- pack A: [input | prev_h] -> bf16 [16384][2048] ----------------
__global__ __launch_bounds__(256) void pack_a_kernel(const float* __restrict__ input,
                                                     const float* __restrict__ prev_h,
                                                     unsigned short* __restrict__ Apk) {
    long idx = (long)blockIdx.x * 256 + threadIdx.x;
    long e0 = idx * 8;
    int b = (int)(e0 >> 11);
    int k = (int)(e0 & 2047);
    const float* src = (k < 1024) ? (input + (size_t)b * 1024 + k)
                                  : (prev_h + (size_t)b * 1024 + (k - 1024));
    float4 lo = *(const float4*)src;
    float4 hi = *(const float4*)(src + 4);
    u16x8 o;
    o[0] = f2bf(lo.x); o[1] = f2bf(lo.y); o[2] = f2bf(lo.z); o[3] = f2bf(lo.w);
    o[4] = f2bf(hi.x); o[5] = f2bf(hi.y); o[6] = f2bf(hi.z); o[7] = f2bf(hi.w);
    *(u16x8*)(Apk + e0) = o;
}

// ---------------- pack B: per-gate W^T (j-major) bf16 [4][1024][2048] ----------------
__global__ __launch_bounds__(256) void pack_b_kernel(
        const float* __restrict__ wxi, const float* __restrict__ wxf,
        const float* __restrict__ wxo, const float* __restrict__ wxu,
        const float* __restrict__ whi, const float* __restrict__ whf,
        const float* __restrict__ who, const float* __restrict__ whu,
        unsigned short* __restrict__ Bpk) {
    int idx = blockIdx.x * 256 + threadIdx.x;
    int g  = idx >> 18;
    int r  = idx & 262143;
    int kc = r >> 10;
    int j  = r & 1023;
    const float* wx = (g == 0) ? wxi : (g == 1) ? wxf : (g == 2) ? wxo : wxu;
    const float* wh = (g == 0) ? whi : (g == 1) ? whf : (g == 2) ? who : whu;
    int k0 = kc * 8;
    const float* src = (k0 < 1024) ? (wx + (size_t)k0 * 1024 + j)
                                   : (wh + (size_t)(k0 - 1024) * 1024 + j);
    u16x8 o;
#pragma unroll
    for (int t = 0; t < 8; ++t) o[t] = f2bf(src[(size_t)t * 1024]);
    *(u16x8*)(Bpk + (((size_t)(g * 1024 + j)) << 11) + k0) = o;
}

// ---------------- fused GEMM + LSTM epilogue (32x32x16 MFMA, fragment-major LDS) ----------------
// grid 1024 = 64 rowTiles x 16 colTiles; block 512 = 8 waves.
// wave w: wr = w>>1 (64-row quarter), wc = w&1 (32-col half per gate panel).
// Per wave: 64 rows x 32 cols x 4 gates -> acc[2][4] f32x16.
// LDS is FRAGMENT-MAJOR (no swizzle): A [rg=8][ks'=4][lane31]x16B (16 KiB),
// B [g=4][ch=2][ks'=4][lane31]x16B (16 KiB). Every ds_read_b128 is two 512B
// lane-contiguous runs -> conflict-free by construction (R13's XOR key aliased
// 4-way on the 32-row pattern: 2.5e7 conflicts).
// GLL dst is linear per wave (1 KiB chunk = one [rg][ks'-pair]); per-lane SOURCE
// address does the layout transform (allowed: only dst must be linear).
// K-loop: R11's proven free-run slice {STAGE(t+2); 12 ds_read(t); 16 MFMA;
// vmcnt(4); BAR}; 4 x 32 KiB buffers.

#define GLL(gp, lp) __builtin_amdgcn_global_load_lds( \
        (__attribute__((address_space(1))) void*)(gp), \
        (__attribute__((address_space(3))) void*)(lp), 16, 0, 0)

#define BAR() do { asm volatile("" ::: "memory"); __builtin_amdgcn_s_barrier(); \
                   asm volatile("" ::: "memory"); } while (0)

__global__ __launch_bounds__(512, 2) void lstm_gemm_kernel(
        const unsigned short* __restrict__ Apk,   // [16384][2048]
        const unsigned short* __restrict__ Bpk,   // [4][1024][2048] j-major
        const float* __restrict__ prev_c,
        const float* __restrict__ bi, const float* __restrict__ bf_,
        const float* __restrict__ bo, const float* __restrict__ bu,
        float* __restrict__ out_h, float* __restrict__ out_c) {
    __shared__ __align__(16) unsigned char smem[131072];
    const int tid = threadIdx.x;
    const int w = tid >> 6, l = tid & 63;
    const int l31 = l & 31, l5 = l >> 5;
    const int wr = w >> 1, wc = w & 1;

    // XCD-aware bijective swizzle (nwg=1024 % 8 == 0)
    const int bid = blockIdx.x;
    const int sw = ((bid & 7) << 7) + (bid >> 3);
    const int tileRow = sw & 63, tileCol = sw >> 6;
    const int rowBase = tileRow * 256;
    const int jBase = tileCol * 64;

    // fragment read offsets (fragment-major: rg*2048 + ks'*512 + l31*16)
    int aoff[2][2], boff[4][2];
#pragma unroll
    for (int m = 0; m < 2; ++m)
#pragma unroll
        for (int ks = 0; ks < 2; ++ks)
            aoff[m][ks] = (wr * 2 + m) * 2048 + (ks * 2 + l5) * 512 + l31 * 16;
#pragma unroll
    for (int g = 0; g < 4; ++g)
#pragma unroll
        for (int ks = 0; ks < 2; ++ks)
            boff[g][ks] = 16384 + g * 4096 + wc * 2048 + (ks * 2 + l5) * 512 + l31 * 16;

    // staging sources (per-lane layout transform; dst linear per wave)
    // A: wave w covers rg=w; GLL q: ks' = q*2 + l5; row = rowBase + w*32 + l31
    const unsigned short* aSq0 = Apk + (size_t)(rowBase + w * 32 + l31) * 2048 + (0 * 2 + l5) * 8;
    const unsigned short* aSq1 = Apk + (size_t)(rowBase + w * 32 + l31) * 2048 + (1 * 2 + l5) * 8;
    // B: wave w covers g=w>>1, ch=w&1; GLL q: ks' = q*2 + l5; col = jBase + ch*32 + l31
    const size_t bRow = (size_t)((w >> 1) * 1024 + jBase + (w & 1) * 32 + l31) << 11;
    const unsigned short* bSq0 = Bpk + bRow + (0 * 2 + l5) * 8;
    const unsigned short* bSq1 = Bpk + bRow + (1 * 2 + l5) * 8;
    const int aD0 = w * 2048, aD1 = w * 2048 + 1024;
    const int bD0 = 16384 + (w >> 1) * 4096 + (w & 1) * 2048;
    const int bD1 = bD0 + 1024;

#define STAGE4(T) do { const int _bb = ((T) & 3) * 32768; \
        GLL(aSq0 + (size_t)(T) * 32, smem + _bb + aD0); \
        GLL(aSq1 + (size_t)(T) * 32, smem + _bb + aD1); \
        GLL(bSq0 + (size_t)(T) * 32, smem + _bb + bD0); \
        GLL(bSq1 + (size_t)(T) * 32, smem + _bb + bD1); } while (0)

    f32x16 acc[2][4];
#pragma unroll
    for (int m = 0; m < 2; ++m)
#pragma unroll
        for (int g = 0; g < 4; ++g)
#pragma unroll
            for (int q = 0; q < 16; ++q) acc[m][g][q] = 0.f;

    // prologue: stage slices 0,1; drain slice-0 loads (leave slice-1 in flight)
    STAGE4(0); STAGE4(1);
    asm volatile("s_waitcnt vmcnt(4)" ::: "memory");
    BAR();

    auto slice = [&](int t, auto vnc, auto stgc) {
        constexpr int VN = decltype(vnc)::value;   // 4 steady; 0 drain; -1 none
        constexpr bool STG = decltype(stgc)::value;
        const int bt = (t & 3) * 32768;
        if constexpr (STG) STAGE4(t + 2);
        bf16x8 av[2][2], bv[4][2];
#pragma unroll
        for (int m = 0; m < 2; ++m)
#pragma unroll
            for (int ks = 0; ks < 2; ++ks)
                av[m][ks] = *(const bf16x8*)(smem + bt + aoff[m][ks]);
#pragma unroll
        for (int g = 0; g < 4; ++g)
#pragma unroll
            for (int ks = 0; ks < 2; ++ks)
                bv[g][ks] = *(const bf16x8*)(smem + bt + boff[g][ks]);
#pragma unroll
        for (int ks = 0; ks < 2; ++ks)
#pragma unroll
            for (int m = 0; m < 2; ++m)
#pragma unroll
                for (int g = 0; g < 4; ++g)
                    acc[m][g] = __builtin_amdgcn_mfma_f32_32x32x16_bf16(
                        av[m][ks], bv[g][ks], acc[m][g], 0, 0, 0);
        if constexpr (VN == 4)      asm volatile("s_waitcnt vmcnt(4)" ::: "memory");
        else if constexpr (VN == 0) asm volatile("s_waitcnt vmcnt(0)" ::: "memory");
        if constexpr (VN >= 0) BAR();
    };

    using c4 = std::integral_constant<int, 4>;
    using c0 = std::integral_constant<int, 0>;
    using cm = std::integral_constant<int, -1>;
    using bT = std::integral_constant<bool, true>;
    using bF = std::integral_constant<bool, false>;

#pragma unroll 1
    for (int t = 0; t < 62; ++t) slice(t, c4{}, bT{});   // t=61 stages slice 63
    slice(62, c0{}, bF{});
    slice(63, cm{}, bF{});

    // ---- epilogue: lane-local; C/D: col=l31, row=(q&3)+8*(q>>2)+4*l5 ----
    const int colIdx = jBase + wc * 32 + l31;
    const float vbi = bi[colIdx], vbf = bf_[colIdx], vbo = bo[colIdx], vbu = bu[colIdx];
    const int rowB = rowBase + wr * 64 + 4 * l5;
#pragma unroll
    for (int m = 0; m < 2; ++m) {
#pragma unroll
        for (int q = 0; q < 16; ++q) {
            const int row = rowB + m * 32 + (q & 3) + 8 * (q >> 2);
            const size_t idx = (size_t)row * 1024 + colIdx;
            float zi = acc[m][0][q] + vbi;
            float zf = acc[m][1][q] + vbf;
            float zo = acc[m][2][q] + vbo;
            float zu = acc[m][3][q] + vbu;
            float iv = fsig(zi), fv = fsig(zf), ov = fsig(zo), uv = ftanh(zu);
            float cv = fv * prev_c[idx] + iv * uv;
            out_c[idx] = cv;
            out_h[idx] = ov * ftanh(cv);
        }
    }
#undef STAGE4
}

extern "C" void kernel_launch(void* const* d_in, const int* in_sizes, int n_in,
                              void* d_out, int out_size, void* d_ws, size_t ws_size,
                              hipStream_t stream) {
    const float* input  = (const float*)d_in[0];
    const float* prev_h = (const float*)d_in[1];
    const float* prev_c = (const float*)d_in[2];
    const float* wxi = (const float*)d_in[3];
    const float* whi = (const float*)d_in[4];
    const float* wxf = (const float*)d_in[5];
    const float* whf = (const float*)d_in[6];
    const float* wxu = (const float*)d_in[7];
    const float* whu = (const float*)d_in[8];
    const float* wxo = (const float*)d_in[9];
    const float* who = (const float*)d_in[10];
    const float* bi  = (const float*)d_in[11];
    const float* bf_ = (const float*)d_in[12];
    const float* bo  = (const float*)d_in[13];
    const float* bu  = (const float*)d_in[14];

    unsigned short* Apk = (unsigned short*)d_ws;                                  // 64 MiB
    unsigned short* Bpk = (unsigned short*)((char*)d_ws + (size_t)67108864);      // 16 MiB

    float* out_h = (float*)d_out;
    float* out_c = out_h + (size_t)16384 * 1024;

    pack_a_kernel<<<dim3(16384), dim3(256), 0, stream>>>(input, prev_h, Apk);
    pack_b_kernel<<<dim3(4096), dim3(256), 0, stream>>>(wxi, wxf, wxo, wxu,
                                                        whi, whf, who, whu, Bpk);
    lstm_gemm_kernel<<<dim3(1024), dim3(512), 0, stream>>>(Apk, Bpk, prev_c,
                                                           bi, bf_, bo, bu, out_h, out_c);
}

// Round 15
// 349.858 us; speedup vs baseline: 1.1542x; 1.1542x over previous
//
#include <hip/hip_runtime.h>
#include <hip/hip_bf16.h>
#include <stdint.h>
#include <type_traits>

// B=16384, IN=1024, H=1024, K = IN+H = 2048
// Gate order: 0=i, 1=f, 2=o, 3=u
// ws: Apk2 64 MiB @0  — A pre-tiled into LDS chunk order:
//      [rowTile=64][slice=64][rg=8][q=2][lane=64]x16B ; 16B(rg,q,l) =
//      A[rt*256+rg*32+(l&31)][t*32+(q*2+(l>>5))*8 .. +8]
//     Bpk2 16 MiB @64MiB — B (=W^T) pre-tiled likewise:
//      [colTile=16][slice=64][g=4][ch=2][q=2][lane=64]x16B =
//      W_g[k...][ct*64+ch*32+(l&31)] with k = t*32+(q*2+(l>>5))*8 .. +8

typedef short bf16x8 __attribute__((ext_vector_type(8)));
typedef unsigned short u16x8 __attribute__((ext_vector_type(8)));
typedef float f32x16 __attribute__((ext_vector_type(16)));

__device__ __forceinline__ unsigned short f2bf(float f) {
    union { float f; uint32_t u; } v; v.f = f;
    uint32_t r = v.u + 0x7FFFu + ((v.u >> 16) & 1u);   // RNE
    return (unsigned short)(r >> 16);
}

__device__ __forceinline__ float fsig(float x) { return 1.0f / (1.0f + __expf(-x)); }
__device__ __forceinline__ float ftanh(float x) { return 2.0f * fsig(2.0f * x) - 1.0f; }

// ---------------- pack A: [input | prev_h] -> tiled bf16 chunks ----------------
__global__ __launch_bounds__(256) void pack_a_kernel(const float* __restrict__ input,
                                                     const float* __restrict__ prev_h,
                                                     unsigned short* __restrict__ Apk2) {
    int u = blockIdx.x * 256 + threadIdx.x;           // 16B-unit index, 4,194,304 total
    int l = u & 63, q = (u >> 6) & 1, rg = (u >> 7) & 7, t = (u >> 10) & 63, rt = u >> 16;
    int row = rt * 256 + rg * 32 + (l & 31);
    int k0 = t * 32 + (q * 2 + (l >> 5)) * 8;
    const float* src = (k0 < 1024) ? (input + (size_t)row * 1024 + k0)
                                   : (prev_h + (size_t)row * 1024 + (k0 - 1024));
    float4 lo = *(const float4*)src;
    float4 hi = *(const float4*)(src + 4);
    u16x8 o;
    o[0] = f2bf(lo.x); o[1] = f2bf(lo.y); o[2] = f2bf(lo.z); o[3] = f2bf(lo.w);
    o[4] = f2bf(hi.x); o[5] = f2bf(hi.y); o[6] = f2bf(hi.z); o[7] = f2bf(hi.w);
    *(u16x8*)(Apk2 + (size_t)u * 8) = o;              // write coalesced
}

// ---------------- pack B: per-gate W^T -> tiled bf16 chunks ----------------
__global__ __launch_bounds__(256) void pack_b_kernel(
        const float* __restrict__ wxi, const float* __restrict__ wxf,
        const float* __restrict__ wxo, const float* __restrict__ wxu,
        const float* __restrict__ whi, const float* __restrict__ whf,
        const float* __restrict__ who, const float* __restrict__ whu,
        unsigned short* __restrict__ Bpk2) {
    int u = blockIdx.x * 256 + threadIdx.x;           // 1,048,576 units
    int l = u & 63, q = (u >> 6) & 1, ch = (u >> 7) & 1, g = (u >> 8) & 3,
        t = (u >> 10) & 63, ct = u >> 16;
    const float* wx = (g == 0) ? wxi : (g == 1) ? wxf : (g == 2) ? wxo : wxu;
    const float* wh = (g == 0) ? whi : (g == 1) ? whf : (g == 2) ? who : whu;
    int j = ct * 64 + ch * 32 + (l & 31);
    int k0 = t * 32 + (q * 2 + (l >> 5)) * 8;
    const float* src = (k0 < 1024) ? (wx + (size_t)k0 * 1024 + j)
                                   : (wh + (size_t)(k0 - 1024) * 1024 + j);
    u16x8 o;
#pragma unroll
    for (int e = 0; e < 8; ++e) o[e] = f2bf(src[(size_t)e * 1024]);
    *(u16x8*)(Bpk2 + (size_t)u * 8) = o;
}

// ---------------- fused GEMM + LSTM epilogue ----------------
// grid 1024 = 64 rowTiles x 16 colTiles; block 512 = 8 waves.
// wave w: wr = w>>1 (64-row quarter), wc = w&1 (32-col half per gate panel).
// Per wave: 64 rows x 32 cols x 4 gates -> acc[2][4] f32x16 (32x32x16 MFMA).
// LDS fragment-major (conflict-free ds_read_b128: 512B lane-contiguous runs);
// staging sources are LINEAR 1KiB runs (pre-tiled by pack kernels) -> fully
// coalesced GLL. R11 free-run schedule: 4 x 32 KiB buffers, lookahead t+2,
// {STAGE(t+2); 12 ds_read(t); 16 MFMA; vmcnt(4); BAR} per slice.

#define GLL(gp, lp) __builtin_amdgcn_global_load_lds( \
        (__attribute__((address_space(1))) void*)(gp), \
        (__attribute__((address_space(3))) void*)(lp), 16, 0, 0)

#define BAR() do { asm volatile("" ::: "memory"); __builtin_amdgcn_s_barrier(); \
                   asm volatile("" ::: "memory"); } while (0)

__global__ __launch_bounds__(512, 2) void lstm_gemm_kernel(
        const unsigned short* __restrict__ Apk2,
        const unsigned short* __restrict__ Bpk2,
        const float* __restrict__ prev_c,
        const float* __restrict__ bi, const float* __restrict__ bf_,
        const float* __restrict__ bo, const float* __restrict__ bu,
        float* __restrict__ out_h, float* __restrict__ out_c) {
    __shared__ __align__(16) unsigned char smem[131072];
    const int tid = threadIdx.x;
    const int w = tid >> 6, l = tid & 63;
    const int l31 = l & 31, l5 = l >> 5;
    const int wr = w >> 1, wc = w & 1;

    // XCD-aware bijective swizzle (nwg=1024 % 8 == 0)
    const int bid = blockIdx.x;
    const int sw = ((bid & 7) << 7) + (bid >> 3);
    const int tileRow = sw & 63, tileCol = sw >> 6;
    const int rowBase = tileRow * 256;
    const int jBase = tileCol * 64;

    // fragment read offsets (bytes): A rg*2048 + ks'*512 + l31*16 ; B +16384,g*4096,ch*2048
    int aoff[2][2], boff[4][2];
#pragma unroll
    for (int m = 0; m < 2; ++m)
#pragma unroll
        for (int ks = 0; ks < 2; ++ks)
            aoff[m][ks] = (wr * 2 + m) * 2048 + (ks * 2 + l5) * 512 + l31 * 16;
#pragma unroll
    for (int g = 0; g < 4; ++g)
#pragma unroll
        for (int ks = 0; ks < 2; ++ks)
            boff[g][ks] = 16384 + g * 4096 + wc * 2048 + (ks * 2 + l5) * 512 + l31 * 16;

    // staging: LINEAR per-wave 1KiB runs (u16 elements; chunk = 8192 elems)
    const unsigned short* aSrc = Apk2 + (size_t)tileRow * 64 * 8192 + w * 1024 + l * 8;
    const unsigned short* bSrc = Bpk2 + (size_t)tileCol * 64 * 8192
                               + (w >> 1) * 2048 + (w & 1) * 1024 + l * 8;
    const int aD = w * 2048;
    const int bD = 16384 + (w >> 1) * 4096 + (w & 1) * 2048;

#define STAGE4(T) do { const int _bb = ((T) & 3) * 32768; \
        const size_t _o = (size_t)(T) * 8192; \
        GLL(aSrc + _o,       smem + _bb + aD); \
        GLL(aSrc + _o + 512, smem + _bb + aD + 1024); \
        GLL(bSrc + _o,       smem + _bb + bD); \
        GLL(bSrc + _o + 512, smem + _bb + bD + 1024); } while (0)

    f32x16 acc[2][4];
#pragma unroll
    for (int m = 0; m < 2; ++m)
#pragma unroll
        for (int g = 0; g < 4; ++g)
#pragma unroll
            for (int q = 0; q < 16; ++q) acc[m][g][q] = 0.f;

    // prologue: stage slices 0,1; drain slice-0 loads (leave slice-1 in flight)
    STAGE4(0); STAGE4(1);
    asm volatile("s_waitcnt vmcnt(4)" ::: "memory");
    BAR();

    auto slice = [&](int t, auto vnc, auto stgc) {
        constexpr int VN = decltype(vnc)::value;   // 4 steady; 0 drain; -1 none
        constexpr bool STG = decltype(stgc)::value;
        const int bt = (t & 3) * 32768;
        if constexpr (STG) STAGE4(t + 2);
        bf16x8 av[2][2], bv[4][2];
#pragma unroll
        for (int m = 0; m < 2; ++m)
#pragma unroll
            for (int ks = 0; ks < 2; ++ks)
                av[m][ks] = *(const bf16x8*)(smem + bt + aoff[m][ks]);
#pragma unroll
        for (int g = 0; g < 4; ++g)
#pragma unroll
            for (int ks = 0; ks < 2; ++ks)
                bv[g][ks] = *(const bf16x8*)(smem + bt + boff[g][ks]);
#pragma unroll
        for (int ks = 0; ks < 2; ++ks)
#pragma unroll
            for (int m = 0; m < 2; ++m)
#pragma unroll
                for (int g = 0; g < 4; ++g)
                    acc[m][g] = __builtin_amdgcn_mfma_f32_32x32x16_bf16(
                        av[m][ks], bv[g][ks], acc[m][g], 0, 0, 0);
        if constexpr (VN == 4)      asm volatile("s_waitcnt vmcnt(4)" ::: "memory");
        else if constexpr (VN == 0) asm volatile("s_waitcnt vmcnt(0)" ::: "memory");
        if constexpr (VN >= 0) BAR();
    };

    using c4 = std::integral_constant<int, 4>;
    using c0 = std::integral_constant<int, 0>;
    using cm = std::integral_constant<int, -1>;
    using bT = std::integral_constant<bool, true>;
    using bF = std::integral_constant<bool, false>;

#pragma unroll 1
    for (int t = 0; t < 62; ++t) slice(t, c4{}, bT{});   // t=61 stages slice 63
    slice(62, c0{}, bF{});
    slice(63, cm{}, bF{});

    // ---- epilogue: lane-local; C/D: col=l31, row=(q&3)+8*(q>>2)+4*l5 ----
    const int colIdx = jBase + wc * 32 + l31;
    const float vbi = bi[colIdx], vbf = bf_[colIdx], vbo = bo[colIdx], vbu = bu[colIdx];
    const int rowB = rowBase + wr * 64 + 4 * l5;
#pragma unroll
    for (int m = 0; m < 2; ++m) {
#pragma unroll
        for (int q = 0; q < 16; ++q) {
            const int row = rowB + m * 32 + (q & 3) + 8 * (q >> 2);
            const size_t idx = (size_t)row * 1024 + colIdx;
            float zi = acc[m][0][q] + vbi;
            float zf = acc[m][1][q] + vbf;
            float zo = acc[m][2][q] + vbo;
            float zu = acc[m][3][q] + vbu;
            float iv = fsig(zi), fv = fsig(zf), ov = fsig(zo), uv = ftanh(zu);
            float cv = fv * prev_c[idx] + iv * uv;
            out_c[idx] = cv;
            out_h[idx] = ov * ftanh(cv);
        }
    }
#undef STAGE4
}

extern "C" void kernel_launch(void* const* d_in, const int* in_sizes, int n_in,
                              void* d_out, int out_size, void* d_ws, size_t ws_size,
                              hipStream_t stream) {
    const float* input  = (const float*)d_in[0];
    const float* prev_h = (const float*)d_in[1];
    const float* prev_c = (const float*)d_in[2];
    const float* wxi = (const float*)d_in[3];
    const float* whi = (const float*)d_in[4];
    const float* wxf = (const float*)d_in[5];
    const float* whf = (const float*)d_in[6];
    const float* wxu = (const float*)d_in[7];
    const float* whu = (const float*)d_in[8];
    const float* wxo = (const float*)d_in[9];
    const float* who = (const float*)d_in[10];
    const float* bi  = (const float*)d_in[11];
    const float* bf_ = (const float*)d_in[12];
    const float* bo  = (const float*)d_in[13];
    const float* bu  = (const float*)d_in[14];

    unsigned short* Apk2 = (unsigned short*)d_ws;                                 // 64 MiB
    unsigned short* Bpk2 = (unsigned short*)((char*)d_ws + (size_t)67108864);     // 16 MiB

    float* out_h = (float*)d_out;
    float* out_c = out_h + (size_t)16384 * 1024;

    pack_a_kernel<<<dim3(16384), dim3(256), 0, stream>>>(input, prev_h, Apk2);
    pack_b_kernel<<<dim3(4096), dim3(256), 0, stream>>>(wxi, wxf, wxo, wxu,
                                                        whi, whf, who, whu, Bpk2);
    lstm_gemm_kernel<<<dim3(1024), dim3(512), 0, stream>>>(Apk2, Bpk2, prev_c,
                                                           bi, bf_, bo, bu, out_h, out_c);
}